// Round 7
// baseline (281.433 us; speedup 1.0000x reference)
//
#include <hip/hip_runtime.h>
#include <hip/hip_bf16.h>

#define B_   8
#define S_   1024
#define HID_ 1024
#define H_   16
#define D_   64

typedef __hip_bfloat16 bf16;
typedef __attribute__((ext_vector_type(8))) short s16x8;   // MFMA A/B frag (8 bf16)
typedef __attribute__((ext_vector_type(4))) float f32x4;   // MFMA C/D frag

// f32 -> bf16 bits, round-half-up (add + shift; 2 VALU)
__device__ __forceinline__ short f2b(float f) {
    union { float f; unsigned u; } a; a.f = f;
    return (short)((a.u + 0x8000u) >> 16);
}
// load 8 consecutive f32 (32B, aligned) -> bf16 half-fragment
__device__ __forceinline__ s16x8 cvt8(const float* p) {
    const float4* q = (const float4*)p;
    float4 u = q[0], v = q[1];
    s16x8 r;
    r[0] = f2b(u.x); r[1] = f2b(u.y); r[2] = f2b(u.z); r[3] = f2b(u.w);
    r[4] = f2b(v.x); r[5] = f2b(v.y); r[6] = f2b(v.z); r[7] = f2b(v.w);
    return r;
}
__device__ __forceinline__ s16x8 load8bf(const bf16* p) {
    return *(const s16x8*)p;   // 16B load; callers guarantee alignment
}

// DPP 16-lane butterfly sum (the 16 lanes of a quad hold one C-row)
template <int CTRL>
__device__ __forceinline__ float dppf(float x) {
    union { float f; int i; } u, r;
    u.f = x;
    r.i = __builtin_amdgcn_update_dpp(u.i, u.i, CTRL, 0xF, 0xF, true);
    return r.f;
}
__device__ __forceinline__ float rowsum16(float x) {
    x += dppf<0xB1>(x);    // quad_perm xor1
    x += dppf<0x4E>(x);    // quad_perm xor2
    x += dppf<0x141>(x);   // row_half_mirror (xor4)
    x += dppf<0x140>(x);   // row_mirror (xor8)
    return x;
}

// ---------------------------------------------------------------------------
// Kernel 0: one-shot W f32 -> bf16.
// ---------------------------------------------------------------------------
__global__ __launch_bounds__(256) void cvt_w(
    const float* __restrict__ Wq, const float* __restrict__ Wk,
    const float* __restrict__ Wv, bf16* __restrict__ Wb)
{
    const float* srcs[3] = {Wq, Wk, Wv};
    const float* src = srcs[blockIdx.y];
    bf16* dst = Wb + (size_t)blockIdx.y * (H_ * D_ * D_);
    const int i = (blockIdx.x * 256 + threadIdx.x) * 8;
    *(s16x8*)(dst + i) = cvt8(src + i);
}

// ---------------------------------------------------------------------------
// Kernel 1: QKV projection. x tile staged through LDS with fully-coalesced
// float4 reads (fixes the 32B-at-4KiB-stride overfetch), converted to bf16
// once per element. W frags from pre-converted bf16. 128 rows/block.
// Q,K: [B,H,S,D]; V transposed VT: [B,H,D,S]. grid (S/128, H, B), block 256.
// ---------------------------------------------------------------------------
__global__ __launch_bounds__(256) void qkv_proj(
    const float* __restrict__ x, const bf16* __restrict__ Wb,
    const float* __restrict__ bq, const float* __restrict__ bk,
    const float* __restrict__ bv,
    bf16* __restrict__ Q, bf16* __restrict__ K, bf16* __restrict__ VT)
{
    __shared__ __align__(16) bf16 xs[128][72];   // 18 KiB, stride-72 padding

    const int sc = blockIdx.x, h = blockIdx.y, b = blockIdx.z;
    const int t = threadIdx.x;
    const int wave = t >> 6, lane = t & 63;
    const int quad = lane >> 4, c = lane & 15;
    const int s0 = sc * 128 + wave * 32;
    const size_t bh = (size_t)b * H_ + h;

    // ---- stage x[s0block..+128)[h*64..+64) -> bf16 LDS, coalesced ----
    {
        const float* xg = x + ((size_t)b * S_ + sc * 128) * HID_ + h * D_;
#pragma unroll
        for (int i = 0; i < 8; ++i) {
            const int j = i * 256 + t;          // 2048 float4 segments
            const int row = j >> 4, seg = j & 15;
            float4 v = *(const float4*)(xg + (size_t)row * HID_ + seg * 4);
            short4 pk;
            pk.x = f2b(v.x); pk.y = f2b(v.y); pk.z = f2b(v.z); pk.w = f2b(v.w);
            *(short4*)&xs[row][seg * 4] = pk;
        }
    }
    __syncthreads();

    // X frags for this wave's 2 row-tiles (A in VT path, B in Q/K path)
    s16x8 xa[2][2];
#pragma unroll
    for (int mt = 0; mt < 2; ++mt) {
        xa[mt][0] = *(const s16x8*)&xs[wave * 32 + mt * 16 + c][quad * 8];
        xa[mt][1] = *(const s16x8*)&xs[wave * 32 + mt * 16 + c][32 + quad * 8];
    }

    const float* bs[3] = {bq, bk, bv};

#pragma unroll
    for (int m = 0; m < 3; ++m) {
        const bf16*  W    = Wb + ((size_t)m * H_ + h) * (D_ * D_);
        const float* bias = bs[m] + h * D_;
#pragma unroll
        for (int et = 0; et < 4; ++et) {
            const bf16* wrow = W + (et * 16 + c) * D_ + quad * 8;
            s16x8 wf0 = load8bf(wrow);
            s16x8 wf1 = load8bf(wrow + 32);
            if (m < 2) {
                // D[e][s] = W·X^T : col = s (lane c), row = e (quad*4+r)
                const float4 bb = *(const float4*)&bias[et * 16 + quad * 4];
#pragma unroll
                for (int mt = 0; mt < 2; ++mt) {
                    f32x4 acc = {0.f, 0.f, 0.f, 0.f};
                    acc = __builtin_amdgcn_mfma_f32_16x16x32_bf16(wf0, xa[mt][0], acc, 0, 0, 0);
                    acc = __builtin_amdgcn_mfma_f32_16x16x32_bf16(wf1, xa[mt][1], acc, 0, 0, 0);
                    bf16* dst = (m == 0 ? Q : K) +
                        (bh * S_ + s0 + mt * 16 + c) * D_ + et * 16 + quad * 4;
                    short4 pk;
                    pk.x = f2b(acc[0] + bb.x);
                    pk.y = f2b(acc[1] + bb.y);
                    pk.z = f2b(acc[2] + bb.z);
                    pk.w = f2b(acc[3] + bb.w);
                    *(short4*)dst = pk;
                }
            } else {
                // D[s][e] = X·W^T : col = e (lane c), row = s (quad*4+r)
                const float bbv = bias[et * 16 + c];
#pragma unroll
                for (int mt = 0; mt < 2; ++mt) {
                    f32x4 acc = {0.f, 0.f, 0.f, 0.f};
                    acc = __builtin_amdgcn_mfma_f32_16x16x32_bf16(xa[mt][0], wf0, acc, 0, 0, 0);
                    acc = __builtin_amdgcn_mfma_f32_16x16x32_bf16(xa[mt][1], wf1, acc, 0, 0, 0);
                    bf16* dst = VT + (bh * D_ + et * 16 + c) * S_ + s0 + mt * 16 + quad * 4;
                    short4 pk;
                    pk.x = f2b(acc[0] + bbv);
                    pk.y = f2b(acc[1] + bbv);
                    pk.z = f2b(acc[2] + bbv);
                    pk.w = f2b(acc[3] + bbv);
                    *(short4*)dst = pk;
                }
            }
        }
    }
}

// ---------------------------------------------------------------------------
// Kernel 2: MFMA flash attention, fixed-shift softmax, XCD-local scheduling.
// 1D grid of 1024; bh = id&127, qc = id>>7. Since workgroup->XCD assignment
// round-robins on linear block id (id%8), all 8 q-chunks of one (b,h) share
// an XCD: K/V (256 KiB/bh, 16 bh/XCD = 4 MiB) stays L2-resident instead of
// being fetched 8x from HBM. Epilogue transposes O through wave-private LDS
// (union with the P tile) to emit contiguous per-lane float4 stores.
// ---------------------------------------------------------------------------
__global__ __launch_bounds__(256, 3) void attn(
    const bf16* __restrict__ Q, const bf16* __restrict__ K,
    const bf16* __restrict__ VT, float* __restrict__ out)
{
    // wave-private buffer: P tile (bf16 [32][72]) unioned with O-staging
    // (f32 [16][68]); no cross-wave sharing, so no barriers needed.
    union WB { short p[32][72]; float os[16][68]; };
    __shared__ __align__(16) WB wb[4];

    const int id = blockIdx.x;
    const int bh_i = id & 127, qc = id >> 7;
    const int b = bh_i >> 4, h = bh_i & 15;
    const int wave = threadIdx.x >> 6, lane = threadIdx.x & 63;
    const int quad = lane >> 4, c = lane & 15;
    const int q0 = qc * 128 + wave * 32;
    const size_t bh = (size_t)b * H_ + h;

    s16x8 aq[2][2];
#pragma unroll
    for (int mt = 0; mt < 2; ++mt) {
        const bf16* qrow = Q + (bh * S_ + q0 + mt * 16 + c) * D_ + quad * 8;
        aq[mt][0] = load8bf(qrow);
        aq[mt][1] = load8bf(qrow + 32);
    }

    f32x4 o[2][4];
#pragma unroll
    for (int mt = 0; mt < 2; ++mt)
#pragma unroll
        for (int et = 0; et < 4; ++et) o[mt][et] = {0.f, 0.f, 0.f, 0.f};
    float l[2][4];
#pragma unroll
    for (int mt = 0; mt < 2; ++mt)
#pragma unroll
        for (int r = 0; r < 4; ++r) l[mt][r] = 0.f;

    const float CEXP = 0.18033688011112042f;   // (1/sqrt(64)) * log2(e)
    const float NM0  = -16.0f * 0.18033688011112042f;  // fixed shift m0=16

    const bf16* Kbase = K  + bh * (size_t)(S_ * D_) + c * D_ + quad * 8;
    const bf16* Vbase = VT + bh * (size_t)(D_ * S_);

    s16x8 ka[4], kb[4];
#pragma unroll
    for (int ct = 0; ct < 4; ++ct) {
        ka[ct] = load8bf(Kbase + ct * 16 * D_);
        kb[ct] = load8bf(Kbase + ct * 16 * D_ + 32);
    }

#pragma unroll 2
    for (int kt = 0; kt < S_ / 64; ++kt) {
        // ---- issue V(kt) loads; consumed at the bottom ----
        s16x8 va[4], vb[4];
        const bf16* Vt0 = Vbase + kt * 64;
#pragma unroll
        for (int et = 0; et < 4; ++et) {
            va[et] = load8bf(Vt0 + (et * 16 + c) * S_ + quad * 8);
            vb[et] = load8bf(Vt0 + (et * 16 + c) * S_ + 32 + quad * 8);
        }

        // ---- S = Q K^T from preloaded K frags ----
        f32x4 s[2][4];
#pragma unroll
        for (int mt = 0; mt < 2; ++mt)
#pragma unroll
            for (int ct = 0; ct < 4; ++ct) {
                f32x4 acc = {0.f, 0.f, 0.f, 0.f};
                acc = __builtin_amdgcn_mfma_f32_16x16x32_bf16(aq[mt][0], ka[ct], acc, 0, 0, 0);
                acc = __builtin_amdgcn_mfma_f32_16x16x32_bf16(aq[mt][1], kb[ct], acc, 0, 0, 0);
                s[mt][ct] = acc;
            }

        // ---- issue K(kt+1) loads (covered by softmax+PV) ----
        {
            const bf16* Kn = Kbase + (size_t)(((kt + 1) & 15) * 64) * D_;
#pragma unroll
            for (int ct = 0; ct < 4; ++ct) {
                ka[ct] = load8bf(Kn + ct * 16 * D_);
                kb[ct] = load8bf(Kn + ct * 16 * D_ + 32);
            }
        }

        // ---- fixed-shift softmax numerator; P -> wave-private LDS ----
#pragma unroll
        for (int mt = 0; mt < 2; ++mt)
#pragma unroll
            for (int ct = 0; ct < 4; ++ct)
#pragma unroll
                for (int r = 0; r < 4; ++r) {
                    float p = __builtin_amdgcn_exp2f(
                        fmaf(s[mt][ct][r], CEXP, NM0));
                    l[mt][r] += p;
                    wb[wave].p[mt * 16 + quad * 4 + r][ct * 16 + c] = f2b(p);
                }

        // ---- O += P V ----
#pragma unroll
        for (int mt = 0; mt < 2; ++mt) {
            s16x8 ap0 = *(const s16x8*)&wb[wave].p[mt * 16 + c][quad * 8];
            s16x8 ap1 = *(const s16x8*)&wb[wave].p[mt * 16 + c][32 + quad * 8];
#pragma unroll
            for (int et = 0; et < 4; ++et) {
                o[mt][et] = __builtin_amdgcn_mfma_f32_16x16x32_bf16(ap0, va[et], o[mt][et], 0, 0, 0);
                o[mt][et] = __builtin_amdgcn_mfma_f32_16x16x32_bf16(ap1, vb[et], o[mt][et], 0, 0, 0);
            }
        }
    }

    // ---- epilogue: rowsum, normalize, transpose via LDS, float4 stores ----
    float inv[2][4];
#pragma unroll
    for (int mt = 0; mt < 2; ++mt)
#pragma unroll
        for (int r = 0; r < 4; ++r)
            inv[mt][r] = 1.0f / rowsum16(l[mt][r]);

#pragma unroll
    for (int mt = 0; mt < 2; ++mt) {
        // scatter C-layout values into wave-private f32 staging
#pragma unroll
        for (int et = 0; et < 4; ++et)
#pragma unroll
            for (int r = 0; r < 4; ++r)
                wb[wave].os[quad * 4 + r][et * 16 + c] = o[mt][et][r] * inv[mt][r];
        // gather rows: lane handles 4 float4 segments of row c (contiguous 16B)
        float* orow = out + ((size_t)b * S_ + q0 + mt * 16 + c) * HID_ + h * D_;
#pragma unroll
        for (int j = 0; j < 4; ++j) {
            float4 v = *(const float4*)&wb[wave].os[c][(quad + j * 4) * 4];
            *(float4*)(orow + (quad + j * 4) * 4) = v;
        }
    }
}

// ---------------------------------------------------------------------------
extern "C" void kernel_launch(void* const* d_in, const int* in_sizes, int n_in,
                              void* d_out, int out_size, void* d_ws, size_t ws_size,
                              hipStream_t stream) {
    (void)in_sizes; (void)n_in; (void)out_size; (void)ws_size;
    const float* x  = (const float*)d_in[0];
    const float* Wq = (const float*)d_in[1];
    const float* bq = (const float*)d_in[2];
    const float* Wk = (const float*)d_in[3];
    const float* bk = (const float*)d_in[4];
    const float* Wv = (const float*)d_in[5];
    const float* bv = (const float*)d_in[6];
    float* outp = (float*)d_out;   // reference output dtype is float32

    const size_t nelem = (size_t)B_ * H_ * S_ * D_;   // 8M elems
    bf16* Qw  = (bf16*)d_ws;
    bf16* Kw  = Qw + nelem;
    bf16* VTw = Kw + nelem;
    bf16* Wbw = VTw + nelem;       // 3*H*D*D bf16 = 384 KiB extra

    cvt_w<<<dim3(32, 3), 256, 0, stream>>>(Wq, Wk, Wv, Wbw);
    dim3 grid(S_ / 128, H_, B_);
    qkv_proj<<<grid, 256, 0, stream>>>(x, Wbw, bq, bk, bv, Qw, Kw, VTw);
    attn<<<dim3(1024), 256, 0, stream>>>(Qw, Kw, VTw, outp);
}